// Round 10
// baseline (811.845 us; speedup 1.0000x reference)
//
#include <hip/hip_runtime.h>

#define TT  128
#define CC  256
#define VV  25
#define KK  3
#define GG  9
#define LL  9
#define NCC 60
#define CINN 3
#define TV    (TT*VV)          // 3200 (input x layout)
#define N4    4096             // TC columns: n = t*32+v
#define KDIM2 (CC*GG)          // 2304
#define KS    2                // gemm2 K-split
#define KCH   (KDIM2/KS)       // 1152
#define UR    ((TT+8)*32)      // 4352 Ut2 rows: row = (t+8)*32+v
#define YSTR  104              // LDS Yt row stride (shorts)
#define HSTR  264              // LDS sH row stride (shorts), bank-skewed
#define FSTR  33               // LDS fp32 stage row stride

typedef __attribute__((ext_vector_type(8))) short bf16x8;
typedef __attribute__((ext_vector_type(4))) float f32x4;
typedef unsigned short us16;

__device__ __forceinline__ us16 f2bf(float f) {
    union { float f; unsigned u; } a; a.f = f;
    unsigned r = a.u + 0x7fff + ((a.u >> 16) & 1);
    return (us16)(r >> 16);
}
__device__ __forceinline__ bf16x8 ld8(const us16* p) { return *(const bf16x8*)p; }

// ---------------- merged prep kernel ----------------

#define PN1 (LL*KK*CC*CC)
#define PN2 (LL*CC*CC*GG)
#define PN3 (LL*KK*32*32)
#define PN4 (LL*CC*32)
#define PTOT (PN1+PN2+PN3+PN4)

__global__ void k_prep(const float* __restrict__ Wg, const float* __restrict__ Wt,
                       const float* __restrict__ A, const float* __restrict__ imp,
                       const float* __restrict__ bg,
                       us16* __restrict__ Wgb, us16* __restrict__ Wt2b,
                       us16* __restrict__ AlTb, float* __restrict__ bgAl) {
    int i = blockIdx.x * 256 + threadIdx.x;
    if (i < PN1) {
        Wgb[i] = f2bf(Wg[i]);
    } else if (i < PN1 + PN2) {
        int j = i - PN1;
        int kk = j % (CC*GG);
        int o  = (j / (CC*GG)) % CC;
        int l  = j / (CC*CC*GG);
        int g = kk >> 8, c = kk & 255;
        Wt2b[j] = f2bf(Wt[((size_t)(l*CC + o)*CC + c)*GG + g]);
    } else if (i < PN1 + PN2 + PN3) {
        int j = i - PN1 - PN2;
        int v = j & 31, w = (j >> 5) & 31;
        int lk = j >> 10, k = lk % KK, l = lk / KK;
        float val = 0.f;
        if (v < VV && w < VV)
            val = A[(k*VV+v)*VV + w] * imp[((size_t)(l*KK+k)*VV+v)*VV + w];
        AlTb[j] = f2bf(val);
    } else if (i < PTOT) {
        int j = i - PN1 - PN2 - PN3;
        int w = j & 31, c = (j >> 5) & 255, l = j >> 13;
        float s = 0.f;
        if (w < VV) {
            for (int k = 0; k < KK; k++) {
                float col = 0.f;
                for (int v = 0; v < VV; v++)
                    col += A[(k*VV+v)*VV + w] * imp[((size_t)(l*KK+k)*VV+v)*VV + w];
                s += bg[l*KK*CC + k*CC + c] * col;
            }
        }
        bgAl[j] = s;
    }
}

// ---------------- block reduce (sum, sumsq) ----------------

__device__ __forceinline__ void blk_reduce2(float& s, float& q, float* red) {
    #pragma unroll
    for (int off = 32; off; off >>= 1) {
        s += __shfl_down(s, off);
        q += __shfl_down(q, off);
    }
    int lane = threadIdx.x & 63, w = threadIdx.x >> 6;
    if (lane == 0) { red[w] = s; red[4+w] = q; }
    __syncthreads();
    s = red[0]+red[1]+red[2]+red[3];
    q = red[4]+red[5]+red[6]+red[7];
}

// ---------------- fused gcn ----------------
// One block per frame (blocks 128..135 write the 8 history pad rows).
// FIRST=1: prologue computes h^0 = fcn_in(LN_in(x_t)).
// FIRST=0: prologue computes h^l = relu(LN2(sum_ks TCp + bt) + HresidT(t-4)).
// Prologue result -> sH (LDS, B-operand layout) + HT (fp32, next residual).
// Then: Y = Wg@h (MFMA, B register-cached) -> adjacency (MFMA) -> LN1 -> Ut2.

template<int FIRST>
__global__ __launch_bounds__(256) void k_gcn(
    const float* __restrict__ x, const float* __restrict__ lniw,
    const float* __restrict__ lnib, const float* __restrict__ Win,
    const float* __restrict__ bin,
    const float* __restrict__ TCp, const float* __restrict__ btv,
    const float* __restrict__ ln2w, const float* __restrict__ ln2b,
    const float* __restrict__ HresidT,
    const us16* __restrict__ Wgb,
    const us16* __restrict__ AlTb, const float* __restrict__ bgAl,
    const float* __restrict__ lnw, const float* __restrict__ lnb,
    float* __restrict__ HT, us16* __restrict__ Ut2) {

    const int t = blockIdx.x, tid = threadIdx.x;
    if (t >= TT) {                     // 8 history pad frames: relu(ln1_b)
        int tp = t - TT, c = tid;
        #pragma unroll
        for (int w = 0; w < 32; w++) {
            float u = (w < VV) ? fmaxf(lnb[c*VV + w], 0.f) : 0.f;
            Ut2[(size_t)(tp*32 + w)*CC + c] = f2bf(u);
        }
        return;
    }
    __shared__ __align__(16) us16 pool[CC*YSTR];   // Yt (53.2KB) / sF (33.8KB) overlay
    __shared__ __align__(16) us16 sH[32*HSTR];     // 16.9 KB
    __shared__ float red[8];
    __shared__ float sx[80];
    __shared__ float sh[80];
    const int wave = tid >> 6, lane = tid & 63, quad = lane >> 4, l16 = lane & 15;

    if (FIRST) {
        // ---- h^0 = W_in @ LN_in(x_t) + b_in ----
        if (tid < CINN*VV)
            sx[tid] = x[(size_t)(tid/VV)*TV + t*VV + (tid%VV)];
        __syncthreads();
        float s = 0.f, q = 0.f;
        for (int i = 0; i < CINN*VV; i++) { float v = sx[i]; s += v; q += v*v; }
        float m  = s * (1.f/75.f);
        float var = q * (1.f/75.f) - m*m;
        float rs = rsqrtf(var + 1e-5f);
        if (tid < CINN*VV)
            sh[tid] = (sx[tid]-m)*rs*lniw[tid] + lnib[tid];
        __syncthreads();
        int c = tid;
        float w0 = Win[c*3+0], w1 = Win[c*3+1], w2 = Win[c*3+2], bb = bin[c];
        #pragma unroll
        for (int v = 0; v < VV; v++) {
            float acc = bb + w0*sh[v] + w1*sh[VV+v] + w2*sh[2*VV+v];
            HT[(size_t)(t*32 + v)*CC + c] = acc;
            sH[v*HSTR + c] = f2bf(acc);
        }
        #pragma unroll
        for (int v = VV; v < 32; v++)
            sH[v*HSTR + c] = 0;
        __syncthreads();
    } else {
        // ---- h^l = relu(LN2(sum TCp + bt) + resid) ----
        float* sF = (float*)pool;
        #pragma unroll
        for (int j = 0; j < 8; j++) {
            int cs = j*32 + (tid >> 3);
            int v4 = (tid & 7) * 4;
            size_t base = (size_t)cs*N4 + t*32 + v4;
            float4 xv = *(const float4*)(TCp + base);
            float4 yv = *(const float4*)(TCp + (size_t)CC*N4 + base);
            sF[cs*FSTR + v4+0] = xv.x + yv.x; sF[cs*FSTR + v4+1] = xv.y + yv.y;
            sF[cs*FSTR + v4+2] = xv.z + yv.z; sF[cs*FSTR + v4+3] = xv.w + yv.w;
        }
        __syncthreads();
        int c = tid;
        float btc = btv[c];
        float vals[VV];
        float s = 0.f, q = 0.f;
        #pragma unroll
        for (int v = 0; v < VV; v++) {
            float xv = sF[c*FSTR + v] + btc;
            vals[v] = xv; s += xv; q += xv*xv;
        }
        blk_reduce2(s, q, red);
        float m = s * (1.f/6400.f);
        float var = q * (1.f/6400.f) - m*m;
        float rs = rsqrtf(var + 1e-5f);
        #pragma unroll
        for (int v = 0; v < VV; v++) {
            float res = (t >= 4) ? HresidT[(size_t)((t-4)*32 + v)*CC + c] : 0.f;
            float o = fmaxf((vals[v]-m)*rs*ln2w[c*VV+v] + ln2b[c*VV+v] + res, 0.f);
            HT[(size_t)(t*32 + v)*CC + c] = o;
            sH[v*HSTR + c] = f2bf(o);
        }
        #pragma unroll
        for (int v = VV; v < 32; v++)
            sH[v*HSTR + c] = 0;
        __syncthreads();
    }

    // ---- phase 1: Y = Wg @ h  (M=768, N=32, K=256), B register-cached from sH ----
    us16* Yt = pool;
    bf16x8 bf[2][8];
    #pragma unroll
    for (int nt = 0; nt < 2; nt++)
        #pragma unroll
        for (int s = 0; s < 8; s++)
            bf[nt][s] = *(const bf16x8*)(sH + (nt*16 + l16)*HSTR + s*32 + quad*8);
    f32x4 acc[12][2];
    #pragma unroll
    for (int mt = 0; mt < 12; mt++) { acc[mt][0] = (f32x4){}; acc[mt][1] = (f32x4){}; }
    #pragma unroll
    for (int mt = 0; mt < 12; mt++) {
        const us16* ap = Wgb + (size_t)(wave*192 + mt*16 + l16)*CC + quad*8;
        #pragma unroll
        for (int s = 0; s < 8; s++) {
            bf16x8 a = ld8(ap + s*32);
            acc[mt][0] = __builtin_amdgcn_mfma_f32_16x16x32_bf16(a, bf[0][s], acc[mt][0], 0,0,0);
            acc[mt][1] = __builtin_amdgcn_mfma_f32_16x16x32_bf16(a, bf[1][s], acc[mt][1], 0,0,0);
        }
    }
    __syncthreads();   // pool: sF -> Yt reuse
    #pragma unroll
    for (int mt = 0; mt < 12; mt++)
        #pragma unroll
        for (int nt = 0; nt < 2; nt++)
            #pragma unroll
            for (int r = 0; r < 4; r++) {
                int m = wave*192 + mt*16 + quad*4 + r;
                Yt[(m & 255)*YSTR + (m >> 8)*32 + nt*16 + l16] = f2bf(acc[mt][nt][r]);
            }
    __syncthreads();

    // ---- phase 2: Z[c][w] = sum_{k,v} Yt[c][k*32+v] * Al[k][v][w] ----
    bf16x8 al[2][3];
    #pragma unroll
    for (int nt = 0; nt < 2; nt++)
        #pragma unroll
        for (int s = 0; s < 3; s++)
            al[nt][s] = ld8(AlTb + (size_t)(s*32 + nt*16 + l16)*32 + quad*8);
    f32x4 z[4][2];
    #pragma unroll
    for (int mt = 0; mt < 4; mt++) { z[mt][0] = (f32x4){}; z[mt][1] = (f32x4){}; }
    #pragma unroll
    for (int mt = 0; mt < 4; mt++)
        #pragma unroll
        for (int s = 0; s < 3; s++) {
            bf16x8 a = *(const bf16x8*)(Yt + (wave*64 + mt*16 + l16)*YSTR + s*32 + quad*8);
            z[mt][0] = __builtin_amdgcn_mfma_f32_16x16x32_bf16(a, al[0][s], z[mt][0], 0,0,0);
            z[mt][1] = __builtin_amdgcn_mfma_f32_16x16x32_bf16(a, al[1][s], z[mt][1], 0,0,0);
        }

    // ---- bias fold + LN1 + ReLU -> Ut2 ----
    float s_ = 0.f, q_ = 0.f;
    #pragma unroll
    for (int mt = 0; mt < 4; mt++)
        #pragma unroll
        for (int nt = 0; nt < 2; nt++)
            #pragma unroll
            for (int r = 0; r < 4; r++) {
                int c = wave*64 + mt*16 + quad*4 + r;
                int w = nt*16 + l16;
                float zb = z[mt][nt][r] + bgAl[c*32 + w];
                z[mt][nt][r] = zb;
                if (w < VV) { s_ += zb; q_ += zb*zb; }
            }
    blk_reduce2(s_, q_, red);
    float m = s_ * (1.f/6400.f);
    float var = q_ * (1.f/6400.f) - m*m;
    float rs = rsqrtf(var + 1e-5f);
    #pragma unroll
    for (int mt = 0; mt < 4; mt++)
        #pragma unroll
        for (int nt = 0; nt < 2; nt++) {
            int w = nt*16 + l16;
            if (w < VV) {
                int c0 = wave*64 + mt*16 + quad*4;
                ushort4 pk;
                float u0 = fmaxf((z[mt][nt][0]-m)*rs*lnw[(c0+0)*VV+w] + lnb[(c0+0)*VV+w], 0.f);
                float u1 = fmaxf((z[mt][nt][1]-m)*rs*lnw[(c0+1)*VV+w] + lnb[(c0+1)*VV+w], 0.f);
                float u2 = fmaxf((z[mt][nt][2]-m)*rs*lnw[(c0+2)*VV+w] + lnb[(c0+2)*VV+w], 0.f);
                float u3 = fmaxf((z[mt][nt][3]-m)*rs*lnw[(c0+3)*VV+w] + lnb[(c0+3)*VV+w], 0.f);
                pk.x = f2bf(u0); pk.y = f2bf(u1); pk.z = f2bf(u2); pk.w = f2bf(u3);
                *(ushort4*)(Ut2 + (size_t)((t+8)*32 + w)*CC + c0) = pk;
            }
        }
    #pragma unroll
    for (int r = VV; r < 32; r++)
        Ut2[(size_t)((t+8)*32 + r)*CC + tid] = 0;
}

// ---------------- GEMM2: partial TC = Wt2 @ Ushift, K-split x2 ----------------
// Named-register double buffer (no arrays -> compiler cannot collapse the
// pipeline; 8 x 1KB loads stay in flight per wave). 512 blocks, 2 blocks/CU.

__global__ __launch_bounds__(256, 2) void k_gemm2(const us16* __restrict__ A,
                                                  const us16* __restrict__ Ut2,
                                                  float* __restrict__ TCp) {
    const int tid = threadIdx.x;
    const int wave = tid >> 6, lane = tid & 63, quad = lane >> 4, l16 = lane & 15;
    const int m0w = blockIdx.y * 64 + (wave & 1) * 32;
    const int n0w = blockIdx.x * 64 + (wave >> 1) * 32;
    const int kbeg = blockIdx.z * KCH;
    float* TC = TCp + (size_t)blockIdx.z * CC * N4;
    const us16* ap = A + (size_t)(m0w + l16) * KDIM2 + quad * 8;
    f32x4 acc00 = {}, acc01 = {}, acc10 = {}, acc11 = {};

    bf16x8 xa0, xa1, xb0, xb1;   // stage X
    bf16x8 ya0, ya1, yb0, yb1;   // stage Y

    auto ldc = [&](int k0, bf16x8& A0, bf16x8& A1, bf16x8& B0, bf16x8& B1) {
        A0 = ld8(ap + k0);
        A1 = ld8(ap + k0 + 16*KDIM2);
        int g = k0 >> 8;
        const us16* bp = Ut2 + (size_t)(n0w + (8-g)*32 + l16)*CC + (k0 & 255) + quad*8;
        B0 = ld8(bp);
        B1 = ld8(bp + 16*CC);
    };
    auto mf = [&](bf16x8 A0, bf16x8 A1, bf16x8 B0, bf16x8 B1) {
        acc00 = __builtin_amdgcn_mfma_f32_16x16x32_bf16(A0, B0, acc00, 0,0,0);
        acc01 = __builtin_amdgcn_mfma_f32_16x16x32_bf16(A0, B1, acc01, 0,0,0);
        acc10 = __builtin_amdgcn_mfma_f32_16x16x32_bf16(A1, B0, acc10, 0,0,0);
        acc11 = __builtin_amdgcn_mfma_f32_16x16x32_bf16(A1, B1, acc11, 0,0,0);
    };

    ldc(kbeg,      xa0, xa1, xb0, xb1);
    ldc(kbeg + 32, ya0, ya1, yb0, yb1);
    #pragma unroll 4
    for (int k0 = kbeg + 64; k0 < kbeg + KCH; k0 += 64) {
        mf(xa0, xa1, xb0, xb1);
        ldc(k0, xa0, xa1, xb0, xb1);
        mf(ya0, ya1, yb0, yb1);
        ldc(k0 + 32, ya0, ya1, yb0, yb1);
    }
    mf(xa0, xa1, xb0, xb1);
    mf(ya0, ya1, yb0, yb1);

    const int r0 = m0w + quad*4;
    const int col = n0w + l16;
    #pragma unroll
    for (int r = 0; r < 4; r++) {
        TC[(size_t)(r0 + r)*N4 + col]           = acc00[r];
        TC[(size_t)(r0 + r)*N4 + col + 16]      = acc01[r];
        TC[(size_t)(r0 + 16 + r)*N4 + col]      = acc10[r];
        TC[(size_t)(r0 + 16 + r)*N4 + col + 16] = acc11[r];
    }
}

// ---------------- final: LN2 + residual + ReLU + pool + classifier ----------------

__global__ __launch_bounds__(256) void k_fin(const float* __restrict__ TCp,
                                             const float* __restrict__ HresidT,
                                             const float* __restrict__ btv,
                                             const float* __restrict__ lnw,
                                             const float* __restrict__ lnb,
                                             const float* __restrict__ Wout,
                                             const float* __restrict__ bout,
                                             float* __restrict__ out) {
    int t = blockIdx.x, tid = threadIdx.x;
    __shared__ float sF[CC*FSTR];
    __shared__ float red[8];
    __shared__ float sp[CC];
    #pragma unroll
    for (int j = 0; j < 8; j++) {
        int cs = j*32 + (tid >> 3);
        int v4 = (tid & 7) * 4;
        size_t base = (size_t)cs*N4 + t*32 + v4;
        float4 xv = *(const float4*)(TCp + base);
        float4 yv = *(const float4*)(TCp + (size_t)CC*N4 + base);
        sF[cs*FSTR + v4+0] = xv.x + yv.x; sF[cs*FSTR + v4+1] = xv.y + yv.y;
        sF[cs*FSTR + v4+2] = xv.z + yv.z; sF[cs*FSTR + v4+3] = xv.w + yv.w;
    }
    __syncthreads();
    int c = tid;
    float btc = btv[c];
    float vals[VV];
    float s = 0.f, q = 0.f;
    #pragma unroll
    for (int v = 0; v < VV; v++) {
        float xv = sF[c*FSTR + v] + btc;
        vals[v] = xv; s += xv; q += xv*xv;
    }
    blk_reduce2(s, q, red);
    float m = s * (1.f/6400.f);
    float var = q * (1.f/6400.f) - m*m;
    float rs = rsqrtf(var + 1e-5f);
    float pl = 0.f;
    #pragma unroll
    for (int v = 0; v < VV; v++) {
        float res = (t >= 4) ? HresidT[(size_t)((t-4)*32 + v)*CC + c] : 0.f;
        float o = fmaxf((vals[v]-m)*rs*lnw[c*VV+v] + lnb[c*VV+v] + res, 0.f);
        pl += o;
    }
    sp[c] = pl * (1.f/VV);
    __syncthreads();
    if (tid < NCC) {
        float a = bout[tid];
        for (int cc = 0; cc < CC; cc++) a = fmaf(Wout[tid*CC+cc], sp[cc], a);
        out[t*NCC + tid] = a;
    }
}

// ---------------- launch ----------------

extern "C" void kernel_launch(void* const* d_in, const int* in_sizes, int n_in,
                              void* d_out, int out_size, void* d_ws, size_t ws_size,
                              hipStream_t stream) {
    const float* x    = (const float*)d_in[0];
    const float* A    = (const float*)d_in[1];
    const float* lniw = (const float*)d_in[2];
    const float* lnib = (const float*)d_in[3];
    const float* Win  = (const float*)d_in[4];
    const float* bin  = (const float*)d_in[5];
    const float* Wg   = (const float*)d_in[6];
    const float* bg   = (const float*)d_in[7];
    const float* ln1w = (const float*)d_in[8];
    const float* ln1b = (const float*)d_in[9];
    const float* Wt   = (const float*)d_in[10];
    const float* bt   = (const float*)d_in[11];
    const float* ln2w = (const float*)d_in[12];
    const float* ln2b = (const float*)d_in[13];
    const float* imp  = (const float*)d_in[14];
    const float* Wout = (const float*)d_in[15];
    const float* bout = (const float*)d_in[16];
    float* out = (float*)d_out;

    float* ws = (float*)d_ws;
    size_t off = 0;
    auto alloc = [&](size_t n) { float* p = ws + off; off += (n + 255) & ~(size_t)255; return p; };
    float* HT0  = alloc((size_t)TT*32*CC);
    float* HT1  = alloc((size_t)TT*32*CC);
    float* TCp  = alloc((size_t)KS*CC*N4);
    float* bgAl = alloc((size_t)LL*CC*32);
    us16* Wgb  = (us16*)alloc((size_t)LL*KK*CC*CC/2);
    us16* Wt2b = (us16*)alloc((size_t)LL*CC*KDIM2/2);
    us16* Ut2  = (us16*)alloc((size_t)UR*CC/2);
    us16* AlTb = (us16*)alloc((size_t)LL*KK*32*32/2);
    (void)ws_size; (void)in_sizes; (void)n_in; (void)out_size;

    k_prep<<<(PTOT + 255)/256, 256, 0, stream>>>(Wg, Wt, A, imp, bg,
                                                 Wgb, Wt2b, AlTb, bgAl);

    float* hPrev = HT0; float* hNext = HT1;   // gcn_l writes h^l; fin reads h^8
    for (int l = 0; l < LL; l++) {
        if (l == 0) {
            k_gcn<1><<<TT + 8, 256, 0, stream>>>(
                x, lniw, lnib, Win, bin,
                TCp, bt, ln2w, ln2b, hPrev,          // unused in FIRST
                Wgb, AlTb, bgAl, ln1w, ln1b,
                hPrev /* writes h^0 */, Ut2);
        } else {
            k_gcn<0><<<TT + 8, 256, 0, stream>>>(
                x, lniw, lnib, Win, bin,
                TCp, bt + (size_t)(l-1)*CC,
                ln2w + (size_t)(l-1)*CC*VV, ln2b + (size_t)(l-1)*CC*VV,
                hPrev /* h^{l-1} residual */,
                Wgb + (size_t)l*KK*CC*CC,
                AlTb + (size_t)l*KK*32*32, bgAl + (size_t)l*CC*32,
                ln1w + (size_t)l*CC*VV, ln1b + (size_t)l*CC*VV,
                hNext /* writes h^l */, Ut2);
            float* tmp = hPrev; hPrev = hNext; hNext = tmp;
        }
        k_gemm2<<<dim3(64, 4, KS), 256, 0, stream>>>(
            Wt2b + (size_t)l*CC*KDIM2, Ut2, TCp);
    }
    k_fin<<<TT, 256, 0, stream>>>(TCp, hPrev,
        bt + (size_t)(LL-1)*CC, ln2w + (size_t)(LL-1)*CC*VV, ln2b + (size_t)(LL-1)*CC*VV,
        Wout, bout, out);
}

// Round 11
// 805.504 us; speedup vs baseline: 1.0079x; 1.0079x over previous
//
#include <hip/hip_runtime.h>

#define TT  128
#define CC  256
#define VV  25
#define KK  3
#define GG  9
#define LL  9
#define NCC 60
#define CINN 3
#define TV    (TT*VV)          // 3200 (input x layout)
#define N4    4096             // Tt rows: n = t*32+v
#define KDIM2 (CC*GG)          // 2304
#define UR    ((TT+8)*32)      // 4352 Ut2 rows: row = (t+8)*32+v
#define YSTR  104              // LDS Yt row stride (shorts)
#define HSTR  264              // LDS sH row stride (shorts), bank-skewed

typedef __attribute__((ext_vector_type(8))) short bf16x8;
typedef __attribute__((ext_vector_type(4))) float f32x4;
typedef unsigned short us16;

__device__ __forceinline__ us16 f2bf(float f) {
    union { float f; unsigned u; } a; a.f = f;
    unsigned r = a.u + 0x7fff + ((a.u >> 16) & 1);
    return (us16)(r >> 16);
}
__device__ __forceinline__ float bf2f(us16 u) {
    union { unsigned u; float f; } a; a.u = ((unsigned)u) << 16; return a.f;
}
__device__ __forceinline__ bf16x8 ld8(const us16* p) { return *(const bf16x8*)p; }

// ---------------- merged prep kernel ----------------

#define PN1 (LL*KK*CC*CC)
#define PN2 (LL*CC*CC*GG)
#define PN3 (LL*KK*32*32)
#define PN4 (LL*CC*32)
#define PTOT (PN1+PN2+PN3+PN4)

__global__ void k_prep(const float* __restrict__ Wg, const float* __restrict__ Wt,
                       const float* __restrict__ A, const float* __restrict__ imp,
                       const float* __restrict__ bg,
                       us16* __restrict__ Wgb, us16* __restrict__ Wt2b,
                       us16* __restrict__ AlTb, float* __restrict__ bgAl) {
    int i = blockIdx.x * 256 + threadIdx.x;
    if (i < PN1) {
        Wgb[i] = f2bf(Wg[i]);
    } else if (i < PN1 + PN2) {
        int j = i - PN1;
        int kk = j % (CC*GG);
        int o  = (j / (CC*GG)) % CC;
        int l  = j / (CC*CC*GG);
        int g = kk >> 8, c = kk & 255;
        Wt2b[j] = f2bf(Wt[((size_t)(l*CC + o)*CC + c)*GG + g]);
    } else if (i < PN1 + PN2 + PN3) {
        int j = i - PN1 - PN2;
        int v = j & 31, w = (j >> 5) & 31;
        int lk = j >> 10, k = lk % KK, l = lk / KK;
        float val = 0.f;
        if (v < VV && w < VV)
            val = A[(k*VV+v)*VV + w] * imp[((size_t)(l*KK+k)*VV+v)*VV + w];
        AlTb[j] = f2bf(val);
    } else if (i < PTOT) {
        int j = i - PN1 - PN2 - PN3;
        int w = j & 31, c = (j >> 5) & 255, l = j >> 13;
        float s = 0.f;
        if (w < VV) {
            for (int k = 0; k < KK; k++) {
                float col = 0.f;
                for (int v = 0; v < VV; v++)
                    col += A[(k*VV+v)*VV + w] * imp[((size_t)(l*KK+k)*VV+v)*VV + w];
                s += bg[l*KK*CC + k*CC + c] * col;
            }
        }
        bgAl[j] = s;
    }
}

// ---------------- block reduce (sum, sumsq) ----------------

__device__ __forceinline__ void blk_reduce2(float& s, float& q, float* red) {
    #pragma unroll
    for (int off = 32; off; off >>= 1) {
        s += __shfl_down(s, off);
        q += __shfl_down(q, off);
    }
    int lane = threadIdx.x & 63, w = threadIdx.x >> 6;
    if (lane == 0) { red[w] = s; red[4+w] = q; }
    __syncthreads();
    s = red[0]+red[1]+red[2]+red[3];
    q = red[4]+red[5]+red[6]+red[7];
}

// ---------------- fused gcn ----------------
// One block per frame (blocks 128..135 write the 8 history pad rows).
// FIRST=1: prologue computes h^0 = fcn_in(LN_in(x_t)).
// FIRST=0: prologue computes h^l = relu(LN2(Tt+bt) + resid(t-4)) reading the
//          bf16 transposed GEMM2 output directly (coalesced 512B rows).
// Prologue result -> sH (LDS, B-operand layout) + HTb (bf16, next residual).

template<int FIRST>
__global__ __launch_bounds__(256) void k_gcn(
    const float* __restrict__ x, const float* __restrict__ lniw,
    const float* __restrict__ lnib, const float* __restrict__ Win,
    const float* __restrict__ bin,
    const us16* __restrict__ Tt, const float* __restrict__ btv,
    const float* __restrict__ ln2w, const float* __restrict__ ln2b,
    const us16* __restrict__ HresidTb,
    const us16* __restrict__ Wgb,
    const us16* __restrict__ AlTb, const float* __restrict__ bgAl,
    const float* __restrict__ lnw, const float* __restrict__ lnb,
    us16* __restrict__ HTb, us16* __restrict__ Ut2) {

    const int t = blockIdx.x, tid = threadIdx.x;
    if (t >= TT) {                     // 8 history pad frames: relu(ln1_b)
        int tp = t - TT, c = tid;
        #pragma unroll
        for (int w = 0; w < 32; w++) {
            float u = (w < VV) ? fmaxf(lnb[c*VV + w], 0.f) : 0.f;
            Ut2[(size_t)(tp*32 + w)*CC + c] = f2bf(u);
        }
        return;
    }
    __shared__ __align__(16) us16 Yt[CC*YSTR];     // 53.2 KB
    __shared__ __align__(16) us16 sH[32*HSTR];     // 16.9 KB
    __shared__ float red[8];
    __shared__ float sx[80];
    __shared__ float sh[80];
    const int wave = tid >> 6, lane = tid & 63, quad = lane >> 4, l16 = lane & 15;

    if (FIRST) {
        // ---- h^0 = W_in @ LN_in(x_t) + b_in ----
        if (tid < CINN*VV)
            sx[tid] = x[(size_t)(tid/VV)*TV + t*VV + (tid%VV)];
        __syncthreads();
        float s = 0.f, q = 0.f;
        for (int i = 0; i < CINN*VV; i++) { float v = sx[i]; s += v; q += v*v; }
        float m  = s * (1.f/75.f);
        float var = q * (1.f/75.f) - m*m;
        float rs = rsqrtf(var + 1e-5f);
        if (tid < CINN*VV)
            sh[tid] = (sx[tid]-m)*rs*lniw[tid] + lnib[tid];
        __syncthreads();
        int c = tid;
        float w0 = Win[c*3+0], w1 = Win[c*3+1], w2 = Win[c*3+2], bb = bin[c];
        #pragma unroll
        for (int v = 0; v < VV; v++) {
            float acc = bb + w0*sh[v] + w1*sh[VV+v] + w2*sh[2*VV+v];
            us16 b = f2bf(acc);
            HTb[(size_t)(t*32 + v)*CC + c] = b;
            sH[v*HSTR + c] = b;
        }
        #pragma unroll
        for (int v = VV; v < 32; v++)
            sH[v*HSTR + c] = 0;
        __syncthreads();
    } else {
        // ---- h^l = relu(LN2(Tt + bt) + resid), direct coalesced reads ----
        int c = tid;
        float btc = btv[c];
        float vals[VV];
        float s = 0.f, q = 0.f;
        #pragma unroll
        for (int v = 0; v < VV; v++) {
            float xv = bf2f(Tt[(size_t)(t*32 + v)*CC + c]) + btc;
            vals[v] = xv; s += xv; q += xv*xv;
        }
        blk_reduce2(s, q, red);
        float m = s * (1.f/6400.f);
        float var = q * (1.f/6400.f) - m*m;
        float rs = rsqrtf(var + 1e-5f);
        #pragma unroll
        for (int v = 0; v < VV; v++) {
            float res = (t >= 4) ? bf2f(HresidTb[(size_t)((t-4)*32 + v)*CC + c]) : 0.f;
            float o = fmaxf((vals[v]-m)*rs*ln2w[c*VV+v] + ln2b[c*VV+v] + res, 0.f);
            us16 b = f2bf(o);
            HTb[(size_t)(t*32 + v)*CC + c] = b;
            sH[v*HSTR + c] = b;
        }
        #pragma unroll
        for (int v = VV; v < 32; v++)
            sH[v*HSTR + c] = 0;
        __syncthreads();
    }

    // ---- phase 1: Y = Wg @ h  (M=768, N=32, K=256), B register-cached from sH ----
    bf16x8 bf[2][8];
    #pragma unroll
    for (int nt = 0; nt < 2; nt++)
        #pragma unroll
        for (int s = 0; s < 8; s++)
            bf[nt][s] = *(const bf16x8*)(sH + (nt*16 + l16)*HSTR + s*32 + quad*8);
    f32x4 acc[12][2];
    #pragma unroll
    for (int mt = 0; mt < 12; mt++) { acc[mt][0] = (f32x4){}; acc[mt][1] = (f32x4){}; }
    #pragma unroll
    for (int mt = 0; mt < 12; mt++) {
        const us16* ap = Wgb + (size_t)(wave*192 + mt*16 + l16)*CC + quad*8;
        #pragma unroll
        for (int s = 0; s < 8; s++) {
            bf16x8 a = ld8(ap + s*32);
            acc[mt][0] = __builtin_amdgcn_mfma_f32_16x16x32_bf16(a, bf[0][s], acc[mt][0], 0,0,0);
            acc[mt][1] = __builtin_amdgcn_mfma_f32_16x16x32_bf16(a, bf[1][s], acc[mt][1], 0,0,0);
        }
    }
    #pragma unroll
    for (int mt = 0; mt < 12; mt++)
        #pragma unroll
        for (int nt = 0; nt < 2; nt++)
            #pragma unroll
            for (int r = 0; r < 4; r++) {
                int m = wave*192 + mt*16 + quad*4 + r;
                Yt[(m & 255)*YSTR + (m >> 8)*32 + nt*16 + l16] = f2bf(acc[mt][nt][r]);
            }
    __syncthreads();

    // ---- phase 2: Z[c][w] = sum_{k,v} Yt[c][k*32+v] * Al[k][v][w] ----
    bf16x8 al[2][3];
    #pragma unroll
    for (int nt = 0; nt < 2; nt++)
        #pragma unroll
        for (int s = 0; s < 3; s++)
            al[nt][s] = ld8(AlTb + (size_t)(s*32 + nt*16 + l16)*32 + quad*8);
    f32x4 z[4][2];
    #pragma unroll
    for (int mt = 0; mt < 4; mt++) { z[mt][0] = (f32x4){}; z[mt][1] = (f32x4){}; }
    #pragma unroll
    for (int mt = 0; mt < 4; mt++)
        #pragma unroll
        for (int s = 0; s < 3; s++) {
            bf16x8 a = *(const bf16x8*)(Yt + (wave*64 + mt*16 + l16)*YSTR + s*32 + quad*8);
            z[mt][0] = __builtin_amdgcn_mfma_f32_16x16x32_bf16(a, al[0][s], z[mt][0], 0,0,0);
            z[mt][1] = __builtin_amdgcn_mfma_f32_16x16x32_bf16(a, al[1][s], z[mt][1], 0,0,0);
        }

    // ---- bias fold + LN1 + ReLU -> Ut2 ----
    float s_ = 0.f, q_ = 0.f;
    #pragma unroll
    for (int mt = 0; mt < 4; mt++)
        #pragma unroll
        for (int nt = 0; nt < 2; nt++)
            #pragma unroll
            for (int r = 0; r < 4; r++) {
                int c = wave*64 + mt*16 + quad*4 + r;
                int w = nt*16 + l16;
                float zb = z[mt][nt][r] + bgAl[c*32 + w];
                z[mt][nt][r] = zb;
                if (w < VV) { s_ += zb; q_ += zb*zb; }
            }
    blk_reduce2(s_, q_, red);
    float m = s_ * (1.f/6400.f);
    float var = q_ * (1.f/6400.f) - m*m;
    float rs = rsqrtf(var + 1e-5f);
    #pragma unroll
    for (int mt = 0; mt < 4; mt++)
        #pragma unroll
        for (int nt = 0; nt < 2; nt++) {
            int w = nt*16 + l16;
            if (w < VV) {
                int c0 = wave*64 + mt*16 + quad*4;
                ushort4 pk;
                float u0 = fmaxf((z[mt][nt][0]-m)*rs*lnw[(c0+0)*VV+w] + lnb[(c0+0)*VV+w], 0.f);
                float u1 = fmaxf((z[mt][nt][1]-m)*rs*lnw[(c0+1)*VV+w] + lnb[(c0+1)*VV+w], 0.f);
                float u2 = fmaxf((z[mt][nt][2]-m)*rs*lnw[(c0+2)*VV+w] + lnb[(c0+2)*VV+w], 0.f);
                float u3 = fmaxf((z[mt][nt][3]-m)*rs*lnw[(c0+3)*VV+w] + lnb[(c0+3)*VV+w], 0.f);
                pk.x = f2bf(u0); pk.y = f2bf(u1); pk.z = f2bf(u2); pk.w = f2bf(u3);
                *(ushort4*)(Ut2 + (size_t)((t+8)*32 + w)*CC + c0) = pk;
            }
        }
    #pragma unroll
    for (int r = VV; r < 32; r++)
        Ut2[(size_t)((t+8)*32 + r)*CC + tid] = 0;
}

// ---------------- GEMM2: Tt = (Wt2 @ Ushift)^T bf16 ----------------
// 256 blocks, XCD-swizzled (bid&7 -> (m-half, n-quarter)) so each XCD's L2
// fetches a 0.59 MB weight slice + a t-contiguous Ut2 quarter.
// 4-deep named-register pipeline (token-pasted scalars, unroll 1 -> the
// compiler cannot collapse the lookahead).

__global__ __launch_bounds__(256) void k_gemm2(const us16* __restrict__ A,
                                               const us16* __restrict__ Ut2,
                                               us16* __restrict__ Tt) {
    __shared__ us16 TL[64*72];
    const int tid = threadIdx.x;
    const int wave = tid >> 6, lane = tid & 63, quad = lane >> 4, l16 = lane & 15;
    const int bid = blockIdx.x;
    const int xcd = bid & 7, grp = bid >> 3;
    const int mt = (xcd >> 2)*2 + (grp & 1);      // 0..3
    const int nt = (xcd & 3)*16 + (grp >> 1);     // 0..63
    const int m0b = mt*64, n0b = nt*64;
    const int m0w = m0b + (wave & 1)*32;
    const int n0w = n0b + (wave >> 1)*32;
    const us16* ap = A + (size_t)(m0w + l16)*KDIM2 + quad*8;
    f32x4 acc00 = {}, acc01 = {}, acc10 = {}, acc11 = {};
    bf16x8 aA0,aA1,bA0,bA1, aB0,aB1,bB0,bB1, aC0,aC1,bC0,bC1, aD0,aD1,bD0,bD1;

#define GLD(S, it) { \
    int k0 = (it)*32; \
    a##S##0 = ld8(ap + k0); \
    a##S##1 = ld8(ap + k0 + 16*KDIM2); \
    int g = k0 >> 8; \
    const us16* bp = Ut2 + (size_t)(n0w + (8-g)*32 + l16)*CC + (k0 & 255) + quad*8; \
    b##S##0 = ld8(bp); \
    b##S##1 = ld8(bp + 16*CC); }
#define GMF(S) { \
    acc00 = __builtin_amdgcn_mfma_f32_16x16x32_bf16(a##S##0, b##S##0, acc00,0,0,0); \
    acc01 = __builtin_amdgcn_mfma_f32_16x16x32_bf16(a##S##0, b##S##1, acc01,0,0,0); \
    acc10 = __builtin_amdgcn_mfma_f32_16x16x32_bf16(a##S##1, b##S##0, acc10,0,0,0); \
    acc11 = __builtin_amdgcn_mfma_f32_16x16x32_bf16(a##S##1, b##S##1, acc11,0,0,0); }

    GLD(A, 0); GLD(B, 1); GLD(C, 2); GLD(D, 3);
    #pragma unroll 1
    for (int it = 4; it <= KDIM2/32 - 4; it += 4) {
        GMF(A); GLD(A, it);
        GMF(B); GLD(B, it+1);
        GMF(C); GLD(C, it+2);
        GMF(D); GLD(D, it+3);
    }
    GMF(A); GMF(B); GMF(C); GMF(D);
#undef GLD
#undef GMF

    // epilogue: bf16 transpose via LDS, coalesced store to Tt[n][c]
    #pragma unroll
    for (int r = 0; r < 4; r++) {
        int mlo = (wave & 1)*32 + quad*4 + r;
        int nlo = (wave >> 1)*32 + l16;
        TL[nlo*72 + mlo]           = f2bf(acc00[r]);
        TL[(nlo+16)*72 + mlo]      = f2bf(acc01[r]);
        TL[nlo*72 + mlo + 16]      = f2bf(acc10[r]);
        TL[(nlo+16)*72 + mlo + 16] = f2bf(acc11[r]);
    }
    __syncthreads();
    #pragma unroll
    for (int u = 0; u < 2; u++) {
        int q2 = tid + u*256;
        int row = q2 >> 3, ch = q2 & 7;
        *(bf16x8*)(Tt + (size_t)(n0b + row)*CC + m0b + ch*8) =
            *(const bf16x8*)(TL + row*72 + ch*8);
    }
}

// ---------------- final: LN2 + residual + ReLU + pool + classifier ----------------

__global__ __launch_bounds__(256) void k_fin(const us16* __restrict__ Tt,
                                             const us16* __restrict__ HresidTb,
                                             const float* __restrict__ btv,
                                             const float* __restrict__ lnw,
                                             const float* __restrict__ lnb,
                                             const float* __restrict__ Wout,
                                             const float* __restrict__ bout,
                                             float* __restrict__ out) {
    int t = blockIdx.x, tid = threadIdx.x;
    __shared__ float red[8];
    __shared__ float sp[CC];
    int c = tid;
    float btc = btv[c];
    float vals[VV];
    float s = 0.f, q = 0.f;
    #pragma unroll
    for (int v = 0; v < VV; v++) {
        float xv = bf2f(Tt[(size_t)(t*32 + v)*CC + c]) + btc;
        vals[v] = xv; s += xv; q += xv*xv;
    }
    blk_reduce2(s, q, red);
    float m = s * (1.f/6400.f);
    float var = q * (1.f/6400.f) - m*m;
    float rs = rsqrtf(var + 1e-5f);
    float pl = 0.f;
    #pragma unroll
    for (int v = 0; v < VV; v++) {
        float res = (t >= 4) ? bf2f(HresidTb[(size_t)((t-4)*32 + v)*CC + c]) : 0.f;
        float o = fmaxf((vals[v]-m)*rs*lnw[c*VV+v] + lnb[c*VV+v] + res, 0.f);
        pl += o;
    }
    sp[c] = pl * (1.f/VV);
    __syncthreads();
    if (tid < NCC) {
        float a = bout[tid];
        for (int cc = 0; cc < CC; cc++) a = fmaf(Wout[tid*CC+cc], sp[cc], a);
        out[t*NCC + tid] = a;
    }
}

// ---------------- launch ----------------

extern "C" void kernel_launch(void* const* d_in, const int* in_sizes, int n_in,
                              void* d_out, int out_size, void* d_ws, size_t ws_size,
                              hipStream_t stream) {
    const float* x    = (const float*)d_in[0];
    const float* A    = (const float*)d_in[1];
    const float* lniw = (const float*)d_in[2];
    const float* lnib = (const float*)d_in[3];
    const float* Win  = (const float*)d_in[4];
    const float* bin  = (const float*)d_in[5];
    const float* Wg   = (const float*)d_in[6];
    const float* bg   = (const float*)d_in[7];
    const float* ln1w = (const float*)d_in[8];
    const float* ln1b = (const float*)d_in[9];
    const float* Wt   = (const float*)d_in[10];
    const float* bt   = (const float*)d_in[11];
    const float* ln2w = (const float*)d_in[12];
    const float* ln2b = (const float*)d_in[13];
    const float* imp  = (const float*)d_in[14];
    const float* Wout = (const float*)d_in[15];
    const float* bout = (const float*)d_in[16];
    float* out = (float*)d_out;

    float* ws = (float*)d_ws;
    size_t off = 0;
    auto alloc = [&](size_t n) { float* p = ws + off; off += (n + 255) & ~(size_t)255; return p; };
    float* bgAl = alloc((size_t)LL*CC*32);
    us16* HTb0 = (us16*)alloc((size_t)TT*32*CC/2);
    us16* HTb1 = (us16*)alloc((size_t)TT*32*CC/2);
    us16* Tt   = (us16*)alloc((size_t)N4*CC/2);
    us16* Wgb  = (us16*)alloc((size_t)LL*KK*CC*CC/2);
    us16* Wt2b = (us16*)alloc((size_t)LL*CC*KDIM2/2);
    us16* Ut2  = (us16*)alloc((size_t)UR*CC/2);
    us16* AlTb = (us16*)alloc((size_t)LL*KK*32*32/2);
    (void)ws_size; (void)in_sizes; (void)n_in; (void)out_size;

    k_prep<<<(PTOT + 255)/256, 256, 0, stream>>>(Wg, Wt, A, imp, bg,
                                                 Wgb, Wt2b, AlTb, bgAl);

    us16* hPrev = HTb0; us16* hNext = HTb1;
    for (int l = 0; l < LL; l++) {
        if (l == 0) {
            k_gcn<1><<<TT + 8, 256, 0, stream>>>(
                x, lniw, lnib, Win, bin,
                Tt, bt, ln2w, ln2b, hPrev,           // unused in FIRST
                Wgb, AlTb, bgAl, ln1w, ln1b,
                hPrev /* writes h^0 */, Ut2);
        } else {
            k_gcn<0><<<TT + 8, 256, 0, stream>>>(
                x, lniw, lnib, Win, bin,
                Tt, bt + (size_t)(l-1)*CC,
                ln2w + (size_t)(l-1)*CC*VV, ln2b + (size_t)(l-1)*CC*VV,
                hPrev /* h^{l-1} residual */,
                Wgb + (size_t)l*KK*CC*CC,
                AlTb + (size_t)l*KK*32*32, bgAl + (size_t)l*CC*32,
                ln1w + (size_t)l*CC*VV, ln1b + (size_t)l*CC*VV,
                hNext /* writes h^l */, Ut2);
            us16* tmp = hPrev; hPrev = hNext; hNext = tmp;
        }
        k_gemm2<<<256, 256, 0, stream>>>(
            Wt2b + (size_t)l*CC*KDIM2, Ut2, Tt);
    }
    k_fin<<<TT, 256, 0, stream>>>(Tt, hPrev,
        bt + (size_t)(LL-1)*CC, ln2w + (size_t)(LL-1)*CC*VV, ln2b + (size_t)(LL-1)*CC*VV,
        Wout, bout, out);
}

// Round 12
// 713.420 us; speedup vs baseline: 1.1380x; 1.1291x over previous
//
#include <hip/hip_runtime.h>

#define TT  128
#define CC  256
#define VV  25
#define KK  3
#define GG  9
#define LL  9
#define NCC 60
#define CINN 3
#define TV    (TT*VV)          // 3200 (input x layout)
#define N4    4096             // Tt rows: n = t*32+v
#define KDIM2 (CC*GG)          // 2304
#define UR    ((TT+8)*32)      // 4352 Ut2 rows: row = (t+8)*32+v
#define YSTR  104              // LDS Yt row stride (shorts)
#define HSTR  264              // LDS sH row stride (shorts), bank-skewed

typedef __attribute__((ext_vector_type(8))) short bf16x8;
typedef __attribute__((ext_vector_type(4))) float f32x4;
typedef unsigned short us16;

__device__ __forceinline__ us16 f2bf(float f) {
    union { float f; unsigned u; } a; a.f = f;
    unsigned r = a.u + 0x7fff + ((a.u >> 16) & 1);
    return (us16)(r >> 16);
}
__device__ __forceinline__ float bf2f(us16 u) {
    union { unsigned u; float f; } a; a.u = ((unsigned)u) << 16; return a.f;
}
__device__ __forceinline__ bf16x8 ld8(const us16* p) { return *(const bf16x8*)p; }

// ---------------- merged prep kernel ----------------

#define PN1 (LL*KK*CC*CC)
#define PN2 (LL*CC*CC*GG)
#define PN3 (LL*KK*32*32)
#define PN4 (LL*CC*32)
#define PTOT (PN1+PN2+PN3+PN4)

__global__ void k_prep(const float* __restrict__ Wg, const float* __restrict__ Wt,
                       const float* __restrict__ A, const float* __restrict__ imp,
                       const float* __restrict__ bg,
                       us16* __restrict__ Wgb, us16* __restrict__ Wt2b,
                       us16* __restrict__ AlTb, float* __restrict__ bgAl) {
    int i = blockIdx.x * 256 + threadIdx.x;
    if (i < PN1) {
        Wgb[i] = f2bf(Wg[i]);
    } else if (i < PN1 + PN2) {
        int j = i - PN1;
        int kk = j % (CC*GG);
        int o  = (j / (CC*GG)) % CC;
        int l  = j / (CC*CC*GG);
        int g = kk >> 8, c = kk & 255;
        Wt2b[j] = f2bf(Wt[((size_t)(l*CC + o)*CC + c)*GG + g]);
    } else if (i < PN1 + PN2 + PN3) {
        int j = i - PN1 - PN2;
        int v = j & 31, w = (j >> 5) & 31;
        int lk = j >> 10, k = lk % KK, l = lk / KK;
        float val = 0.f;
        if (v < VV && w < VV)
            val = A[(k*VV+v)*VV + w] * imp[((size_t)(l*KK+k)*VV+v)*VV + w];
        AlTb[j] = f2bf(val);
    } else if (i < PTOT) {
        int j = i - PN1 - PN2 - PN3;
        int w = j & 31, c = (j >> 5) & 255, l = j >> 13;
        float s = 0.f;
        if (w < VV) {
            for (int k = 0; k < KK; k++) {
                float col = 0.f;
                for (int v = 0; v < VV; v++)
                    col += A[(k*VV+v)*VV + w] * imp[((size_t)(l*KK+k)*VV+v)*VV + w];
                s += bg[l*KK*CC + k*CC + c] * col;
            }
        }
        bgAl[j] = s;
    }
}

// ---------------- block reduce (sum, sumsq) ----------------

__device__ __forceinline__ void blk_reduce2(float& s, float& q, float* red) {
    #pragma unroll
    for (int off = 32; off; off >>= 1) {
        s += __shfl_down(s, off);
        q += __shfl_down(q, off);
    }
    int lane = threadIdx.x & 63, w = threadIdx.x >> 6;
    if (lane == 0) { red[w] = s; red[4+w] = q; }
    __syncthreads();
    s = red[0]+red[1]+red[2]+red[3];
    q = red[4]+red[5]+red[6]+red[7];
}

// ---------------- fused gcn ----------------
// One block per frame (blocks 128..135 write the 8 history pad rows).
// FIRST=1: prologue computes h^0 = fcn_in(LN_in(x_t)).
// FIRST=0: prologue computes h^l = relu(LN2(Tt+bt) + resid(t-4)).
// Phase 1 uses a 3-stage NAMED-register rotation in an unroll-1 loop: stage
// loaded in iteration i is consumed in iteration i+1, so the scheduler must
// keep 24 x 1KB loads in flight (the r8/r11 load-sinking failure mode is
// structurally impossible). Per-mt accumulators are short-lived f32x4 pairs
// written to Yt LDS immediately (no 96-AGPR array).

template<int FIRST>
__global__ __launch_bounds__(256, 1) void k_gcn(
    const float* __restrict__ x, const float* __restrict__ lniw,
    const float* __restrict__ lnib, const float* __restrict__ Win,
    const float* __restrict__ bin,
    const us16* __restrict__ Tt, const float* __restrict__ btv,
    const float* __restrict__ ln2w, const float* __restrict__ ln2b,
    const us16* __restrict__ HresidTb,
    const us16* __restrict__ Wgb,
    const us16* __restrict__ AlTb, const float* __restrict__ bgAl,
    const float* __restrict__ lnw, const float* __restrict__ lnb,
    us16* __restrict__ HTb, us16* __restrict__ Ut2) {

    const int t = blockIdx.x, tid = threadIdx.x;
    if (t >= TT) {                     // 8 history pad frames: relu(ln1_b)
        int tp = t - TT, c = tid;
        #pragma unroll
        for (int w = 0; w < 32; w++) {
            float u = (w < VV) ? fmaxf(lnb[c*VV + w], 0.f) : 0.f;
            Ut2[(size_t)(tp*32 + w)*CC + c] = f2bf(u);
        }
        return;
    }
    __shared__ __align__(16) us16 Yt[CC*YSTR];     // 53.2 KB
    __shared__ __align__(16) us16 sH[32*HSTR];     // 16.9 KB
    __shared__ float red[8];
    __shared__ float sx[80];
    __shared__ float sh[80];
    const int wave = tid >> 6, lane = tid & 63, quad = lane >> 4, l16 = lane & 15;

    if (FIRST) {
        // ---- h^0 = W_in @ LN_in(x_t) + b_in ----
        if (tid < CINN*VV)
            sx[tid] = x[(size_t)(tid/VV)*TV + t*VV + (tid%VV)];
        __syncthreads();
        float s = 0.f, q = 0.f;
        for (int i = 0; i < CINN*VV; i++) { float v = sx[i]; s += v; q += v*v; }
        float m  = s * (1.f/75.f);
        float var = q * (1.f/75.f) - m*m;
        float rs = rsqrtf(var + 1e-5f);
        if (tid < CINN*VV)
            sh[tid] = (sx[tid]-m)*rs*lniw[tid] + lnib[tid];
        __syncthreads();
        int c = tid;
        float w0 = Win[c*3+0], w1 = Win[c*3+1], w2 = Win[c*3+2], bb = bin[c];
        #pragma unroll
        for (int v = 0; v < VV; v++) {
            float acc = bb + w0*sh[v] + w1*sh[VV+v] + w2*sh[2*VV+v];
            us16 b = f2bf(acc);
            HTb[(size_t)(t*32 + v)*CC + c] = b;
            sH[v*HSTR + c] = b;
        }
        #pragma unroll
        for (int v = VV; v < 32; v++)
            sH[v*HSTR + c] = 0;
        __syncthreads();
    } else {
        // ---- h^l = relu(LN2(Tt + bt) + resid), direct coalesced reads ----
        int c = tid;
        float btc = btv[c];
        float vals[VV];
        float s = 0.f, q = 0.f;
        #pragma unroll
        for (int v = 0; v < VV; v++) {
            float xv = bf2f(Tt[(size_t)(t*32 + v)*CC + c]) + btc;
            vals[v] = xv; s += xv; q += xv*xv;
        }
        blk_reduce2(s, q, red);
        float m = s * (1.f/6400.f);
        float var = q * (1.f/6400.f) - m*m;
        float rs = rsqrtf(var + 1e-5f);
        #pragma unroll
        for (int v = 0; v < VV; v++) {
            float res = (t >= 4) ? bf2f(HresidTb[(size_t)((t-4)*32 + v)*CC + c]) : 0.f;
            float o = fmaxf((vals[v]-m)*rs*ln2w[c*VV+v] + ln2b[c*VV+v] + res, 0.f);
            us16 b = f2bf(o);
            HTb[(size_t)(t*32 + v)*CC + c] = b;
            sH[v*HSTR + c] = b;
        }
        #pragma unroll
        for (int v = VV; v < 32; v++)
            sH[v*HSTR + c] = 0;
        __syncthreads();
    }

    // ---- phase 2 operand prefetch (lands during phase 1) ----
    bf16x8 al[2][3];
    #pragma unroll
    for (int nt = 0; nt < 2; nt++)
        #pragma unroll
        for (int s = 0; s < 3; s++)
            al[nt][s] = ld8(AlTb + (size_t)(s*32 + nt*16 + l16)*32 + quad*8);

    // ---- phase 1: Y = Wg @ h  (M=768, N=32, K=256) ----
    bf16x8 bf[2][8];
    #pragma unroll
    for (int nt = 0; nt < 2; nt++)
        #pragma unroll
        for (int s = 0; s < 8; s++)
            bf[nt][s] = *(const bf16x8*)(sH + (nt*16 + l16)*HSTR + s*32 + quad*8);

    bf16x8 wA0,wA1,wA2,wA3,wA4,wA5,wA6,wA7;
    bf16x8 wB0,wB1,wB2,wB3,wB4,wB5,wB6,wB7;
    bf16x8 wC0,wC1,wC2,wC3,wC4,wC5,wC6,wC7;

#define PLD(S, mtv) { \
    const us16* ap_ = Wgb + (size_t)(wave*192 + (mtv)*16 + l16)*CC + quad*8; \
    S##0 = ld8(ap_);       S##1 = ld8(ap_ + 32); \
    S##2 = ld8(ap_ + 64);  S##3 = ld8(ap_ + 96); \
    S##4 = ld8(ap_ + 128); S##5 = ld8(ap_ + 160); \
    S##6 = ld8(ap_ + 192); S##7 = ld8(ap_ + 224); }
#define PMFW(S, mtv) { \
    f32x4 p0a = {}, p0b = {}, p1a = {}, p1b = {}; \
    p0a = __builtin_amdgcn_mfma_f32_16x16x32_bf16(S##0, bf[0][0], p0a,0,0,0); \
    p1a = __builtin_amdgcn_mfma_f32_16x16x32_bf16(S##0, bf[1][0], p1a,0,0,0); \
    p0b = __builtin_amdgcn_mfma_f32_16x16x32_bf16(S##1, bf[0][1], p0b,0,0,0); \
    p1b = __builtin_amdgcn_mfma_f32_16x16x32_bf16(S##1, bf[1][1], p1b,0,0,0); \
    p0a = __builtin_amdgcn_mfma_f32_16x16x32_bf16(S##2, bf[0][2], p0a,0,0,0); \
    p1a = __builtin_amdgcn_mfma_f32_16x16x32_bf16(S##2, bf[1][2], p1a,0,0,0); \
    p0b = __builtin_amdgcn_mfma_f32_16x16x32_bf16(S##3, bf[0][3], p0b,0,0,0); \
    p1b = __builtin_amdgcn_mfma_f32_16x16x32_bf16(S##3, bf[1][3], p1b,0,0,0); \
    p0a = __builtin_amdgcn_mfma_f32_16x16x32_bf16(S##4, bf[0][4], p0a,0,0,0); \
    p1a = __builtin_amdgcn_mfma_f32_16x16x32_bf16(S##4, bf[1][4], p1a,0,0,0); \
    p0b = __builtin_amdgcn_mfma_f32_16x16x32_bf16(S##5, bf[0][5], p0b,0,0,0); \
    p1b = __builtin_amdgcn_mfma_f32_16x16x32_bf16(S##5, bf[1][5], p1b,0,0,0); \
    p0a = __builtin_amdgcn_mfma_f32_16x16x32_bf16(S##6, bf[0][6], p0a,0,0,0); \
    p1a = __builtin_amdgcn_mfma_f32_16x16x32_bf16(S##6, bf[1][6], p1a,0,0,0); \
    p0b = __builtin_amdgcn_mfma_f32_16x16x32_bf16(S##7, bf[0][7], p0b,0,0,0); \
    p1b = __builtin_amdgcn_mfma_f32_16x16x32_bf16(S##7, bf[1][7], p1b,0,0,0); \
    int mb_ = wave*192 + (mtv)*16 + quad*4; \
    _Pragma("unroll") \
    for (int r_ = 0; r_ < 4; r_++) { \
        int m_ = mb_ + r_; \
        int base_ = (m_ & 255)*YSTR + (m_ >> 8)*32 + l16; \
        Yt[base_]      = f2bf(p0a[r_] + p0b[r_]); \
        Yt[base_ + 16] = f2bf(p1a[r_] + p1b[r_]); \
    } }

    PLD(wA, 0); PLD(wB, 1); PLD(wC, 2);
    #pragma unroll 1
    for (int mt = 0; mt < 9; mt += 3) {
        PMFW(wA, mt);     PLD(wA, mt + 3);
        PMFW(wB, mt + 1); PLD(wB, mt + 4);
        PMFW(wC, mt + 2); PLD(wC, mt + 5);
    }
    PMFW(wA, 9); PMFW(wB, 10); PMFW(wC, 11);
#undef PLD
#undef PMFW
    __syncthreads();

    // ---- phase 2: Z[c][w] = sum_{k,v} Yt[c][k*32+v] * Al[k][v][w] ----
    f32x4 z[4][2];
    #pragma unroll
    for (int mt = 0; mt < 4; mt++) { z[mt][0] = (f32x4){}; z[mt][1] = (f32x4){}; }
    #pragma unroll
    for (int mt = 0; mt < 4; mt++)
        #pragma unroll
        for (int s = 0; s < 3; s++) {
            bf16x8 a = *(const bf16x8*)(Yt + (wave*64 + mt*16 + l16)*YSTR + s*32 + quad*8);
            z[mt][0] = __builtin_amdgcn_mfma_f32_16x16x32_bf16(a, al[0][s], z[mt][0], 0,0,0);
            z[mt][1] = __builtin_amdgcn_mfma_f32_16x16x32_bf16(a, al[1][s], z[mt][1], 0,0,0);
        }

    // ---- bias fold + LN1 + ReLU -> Ut2 ----
    float s_ = 0.f, q_ = 0.f;
    #pragma unroll
    for (int mt = 0; mt < 4; mt++)
        #pragma unroll
        for (int nt = 0; nt < 2; nt++)
            #pragma unroll
            for (int r = 0; r < 4; r++) {
                int c = wave*64 + mt*16 + quad*4 + r;
                int w = nt*16 + l16;
                float zb = z[mt][nt][r] + bgAl[c*32 + w];
                z[mt][nt][r] = zb;
                if (w < VV) { s_ += zb; q_ += zb*zb; }
            }
    blk_reduce2(s_, q_, red);
    float m = s_ * (1.f/6400.f);
    float var = q_ * (1.f/6400.f) - m*m;
    float rs = rsqrtf(var + 1e-5f);
    #pragma unroll
    for (int mt = 0; mt < 4; mt++)
        #pragma unroll
        for (int nt = 0; nt < 2; nt++) {
            int w = nt*16 + l16;
            if (w < VV) {
                int c0 = wave*64 + mt*16 + quad*4;
                ushort4 pk;
                float u0 = fmaxf((z[mt][nt][0]-m)*rs*lnw[(c0+0)*VV+w] + lnb[(c0+0)*VV+w], 0.f);
                float u1 = fmaxf((z[mt][nt][1]-m)*rs*lnw[(c0+1)*VV+w] + lnb[(c0+1)*VV+w], 0.f);
                float u2 = fmaxf((z[mt][nt][2]-m)*rs*lnw[(c0+2)*VV+w] + lnb[(c0+2)*VV+w], 0.f);
                float u3 = fmaxf((z[mt][nt][3]-m)*rs*lnw[(c0+3)*VV+w] + lnb[(c0+3)*VV+w], 0.f);
                pk.x = f2bf(u0); pk.y = f2bf(u1); pk.z = f2bf(u2); pk.w = f2bf(u3);
                *(ushort4*)(Ut2 + (size_t)((t+8)*32 + w)*CC + c0) = pk;
            }
        }
    #pragma unroll
    for (int r = VV; r < 32; r++)
        Ut2[(size_t)((t+8)*32 + r)*CC + tid] = 0;
}

// ---------------- GEMM2: Tt = (Wt2 @ Ushift)^T bf16 ----------------

__global__ __launch_bounds__(256) void k_gemm2(const us16* __restrict__ A,
                                               const us16* __restrict__ Ut2,
                                               us16* __restrict__ Tt) {
    __shared__ us16 TL[64*72];
    const int tid = threadIdx.x;
    const int wave = tid >> 6, lane = tid & 63, quad = lane >> 4, l16 = lane & 15;
    const int bid = blockIdx.x;
    const int xcd = bid & 7, grp = bid >> 3;
    const int mt = (xcd >> 2)*2 + (grp & 1);      // 0..3
    const int nt = (xcd & 3)*16 + (grp >> 1);     // 0..63
    const int m0b = mt*64, n0b = nt*64;
    const int m0w = m0b + (wave & 1)*32;
    const int n0w = n0b + (wave >> 1)*32;
    const us16* ap = A + (size_t)(m0w + l16)*KDIM2 + quad*8;
    f32x4 acc00 = {}, acc01 = {}, acc10 = {}, acc11 = {};
    bf16x8 aA0,aA1,bA0,bA1, aB0,aB1,bB0,bB1, aC0,aC1,bC0,bC1, aD0,aD1,bD0,bD1;

#define GLD(S, it) { \
    int k0 = (it)*32; \
    a##S##0 = ld8(ap + k0); \
    a##S##1 = ld8(ap + k0 + 16*KDIM2); \
    int g = k0 >> 8; \
    const us16* bp = Ut2 + (size_t)(n0w + (8-g)*32 + l16)*CC + (k0 & 255) + quad*8; \
    b##S##0 = ld8(bp); \
    b##S##1 = ld8(bp + 16*CC); }
#define GMF(S) { \
    acc00 = __builtin_amdgcn_mfma_f32_16x16x32_bf16(a##S##0, b##S##0, acc00,0,0,0); \
    acc01 = __builtin_amdgcn_mfma_f32_16x16x32_bf16(a##S##0, b##S##1, acc01,0,0,0); \
    acc10 = __builtin_amdgcn_mfma_f32_16x16x32_bf16(a##S##1, b##S##0, acc10,0,0,0); \
    acc11 = __builtin_amdgcn_mfma_f32_16x16x32_bf16(a##S##1, b##S##1, acc11,0,0,0); }

    GLD(A, 0); GLD(B, 1); GLD(C, 2); GLD(D, 3);
    #pragma unroll 1
    for (int it = 4; it <= KDIM2/32 - 4; it += 4) {
        GMF(A); GLD(A, it);
        GMF(B); GLD(B, it+1);
        GMF(C); GLD(C, it+2);
        GMF(D); GLD(D, it+3);
    }
    GMF(A); GMF(B); GMF(C); GMF(D);
#undef GLD
#undef GMF

    // epilogue: bf16 transpose via LDS, coalesced store to Tt[n][c]
    #pragma unroll
    for (int r = 0; r < 4; r++) {
        int mlo = (wave & 1)*32 + quad*4 + r;
        int nlo = (wave >> 1)*32 + l16;
        TL[nlo*72 + mlo]           = f2bf(acc00[r]);
        TL[(nlo+16)*72 + mlo]      = f2bf(acc01[r]);
        TL[nlo*72 + mlo + 16]      = f2bf(acc10[r]);
        TL[(nlo+16)*72 + mlo + 16] = f2bf(acc11[r]);
    }
    __syncthreads();
    #pragma unroll
    for (int u = 0; u < 2; u++) {
        int q2 = tid + u*256;
        int row = q2 >> 3, ch = q2 & 7;
        *(bf16x8*)(Tt + (size_t)(n0b + row)*CC + m0b + ch*8) =
            *(const bf16x8*)(TL + row*72 + ch*8);
    }
}

// ---------------- final: LN2 + residual + ReLU + pool + classifier ----------------

__global__ __launch_bounds__(256) void k_fin(const us16* __restrict__ Tt,
                                             const us16* __restrict__ HresidTb,
                                             const float* __restrict__ btv,
                                             const float* __restrict__ lnw,
                                             const float* __restrict__ lnb,
                                             const float* __restrict__ Wout,
                                             const float* __restrict__ bout,
                                             float* __restrict__ out) {
    int t = blockIdx.x, tid = threadIdx.x;
    __shared__ float red[8];
    __shared__ float sp[CC];
    int c = tid;
    float btc = btv[c];
    float vals[VV];
    float s = 0.f, q = 0.f;
    #pragma unroll
    for (int v = 0; v < VV; v++) {
        float xv = bf2f(Tt[(size_t)(t*32 + v)*CC + c]) + btc;
        vals[v] = xv; s += xv; q += xv*xv;
    }
    blk_reduce2(s, q, red);
    float m = s * (1.f/6400.f);
    float var = q * (1.f/6400.f) - m*m;
    float rs = rsqrtf(var + 1e-5f);
    float pl = 0.f;
    #pragma unroll
    for (int v = 0; v < VV; v++) {
        float res = (t >= 4) ? bf2f(HresidTb[(size_t)((t-4)*32 + v)*CC + c]) : 0.f;
        float o = fmaxf((vals[v]-m)*rs*lnw[c*VV+v] + lnb[c*VV+v] + res, 0.f);
        pl += o;
    }
    sp[c] = pl * (1.f/VV);
    __syncthreads();
    if (tid < NCC) {
        float a = bout[tid];
        for (int cc = 0; cc < CC; cc++) a = fmaf(Wout[tid*CC+cc], sp[cc], a);
        out[t*NCC + tid] = a;
    }
}

// ---------------- launch ----------------

extern "C" void kernel_launch(void* const* d_in, const int* in_sizes, int n_in,
                              void* d_out, int out_size, void* d_ws, size_t ws_size,
                              hipStream_t stream) {
    const float* x    = (const float*)d_in[0];
    const float* A    = (const float*)d_in[1];
    const float* lniw = (const float*)d_in[2];
    const float* lnib = (const float*)d_in[3];
    const float* Win  = (const float*)d_in[4];
    const float* bin  = (const float*)d_in[5];
    const float* Wg   = (const float*)d_in[6];
    const float* bg   = (const float*)d_in[7];
    const float* ln1w = (const float*)d_in[8];
    const float* ln1b = (const float*)d_in[9];
    const float* Wt   = (const float*)d_in[10];
    const float* bt   = (const float*)d_in[11];
    const float* ln2w = (const float*)d_in[12];
    const float* ln2b = (const float*)d_in[13];
    const float* imp  = (const float*)d_in[14];
    const float* Wout = (const float*)d_in[15];
    const float* bout = (const float*)d_in[16];
    float* out = (float*)d_out;

    float* ws = (float*)d_ws;
    size_t off = 0;
    auto alloc = [&](size_t n) { float* p = ws + off; off += (n + 255) & ~(size_t)255; return p; };
    float* bgAl = alloc((size_t)LL*CC*32);
    us16* HTb0 = (us16*)alloc((size_t)TT*32*CC/2);
    us16* HTb1 = (us16*)alloc((size_t)TT*32*CC/2);
    us16* Tt   = (us16*)alloc((size_t)N4*CC/2);
    us16* Wgb  = (us16*)alloc((size_t)LL*KK*CC*CC/2);
    us16* Wt2b = (us16*)alloc((size_t)LL*CC*KDIM2/2);
    us16* Ut2  = (us16*)alloc((size_t)UR*CC/2);
    us16* AlTb = (us16*)alloc((size_t)LL*KK*32*32/2);
    (void)ws_size; (void)in_sizes; (void)n_in; (void)out_size;

    k_prep<<<(PTOT + 255)/256, 256, 0, stream>>>(Wg, Wt, A, imp, bg,
                                                 Wgb, Wt2b, AlTb, bgAl);

    us16* hPrev = HTb0; us16* hNext = HTb1;
    for (int l = 0; l < LL; l++) {
        if (l == 0) {
            k_gcn<1><<<TT + 8, 256, 0, stream>>>(
                x, lniw, lnib, Win, bin,
                Tt, bt, ln2w, ln2b, hPrev,           // unused in FIRST
                Wgb, AlTb, bgAl, ln1w, ln1b,
                hPrev /* writes h^0 */, Ut2);
        } else {
            k_gcn<0><<<TT + 8, 256, 0, stream>>>(
                x, lniw, lnib, Win, bin,
                Tt, bt + (size_t)(l-1)*CC,
                ln2w + (size_t)(l-1)*CC*VV, ln2b + (size_t)(l-1)*CC*VV,
                hPrev /* h^{l-1} residual */,
                Wgb + (size_t)l*KK*CC*CC,
                AlTb + (size_t)l*KK*32*32, bgAl + (size_t)l*CC*32,
                ln1w + (size_t)l*CC*VV, ln1b + (size_t)l*CC*VV,
                hNext /* writes h^l */, Ut2);
            us16* tmp = hPrev; hPrev = hNext; hNext = tmp;
        }
        k_gemm2<<<256, 256, 0, stream>>>(
            Wt2b + (size_t)l*CC*KDIM2, Ut2, Tt);
    }
    k_fin<<<TT, 256, 0, stream>>>(Tt, hPrev,
        bt + (size_t)(LL-1)*CC, ln2w + (size_t)(LL-1)*CC*VV, ln2b + (size_t)(LL-1)*CC*VV,
        Wout, bout, out);
}